// Round 14
// baseline (259.110 us; speedup 1.0000x reference)
//
#include <hip/hip_runtime.h>

#define N_NODES 16384
#define F_IN    128
#define F_HID   256
#define F_OUT   128
#define LN_EPS  1e-5f
#define CAP     128   // ELL slots/row; P(deg>128) ~ 1e-20 for Poisson(32)
#define H0STR   136   // LDS h0 stride (ushorts); 272 B = 17x16 -> 16B-aligned rows
#define H1STR   264   // LDS post-LN stride (ushorts)
#define REPSTR  132   // LDS C2 repack stride (ushorts)

typedef __attribute__((ext_vector_type(8))) short bf16x8;
typedef __attribute__((ext_vector_type(4))) float f32x4;
typedef __attribute__((ext_vector_type(4))) int   i32x4;
typedef __attribute__((ext_vector_type(4))) unsigned u32x4;

__device__ __forceinline__ unsigned short bf16rne(float f) {
    unsigned u = __float_as_uint(f);
    unsigned r = (u + 0x7fffu + ((u >> 16) & 1u)) >> 16;   // round-to-nearest-even
    return (unsigned short)r;
}
__device__ __forceinline__ float bf_lo(unsigned v) { return __uint_as_float(v << 16); }
__device__ __forceinline__ float bf_hi(unsigned v) { return __uint_as_float(v & 0xffff0000u); }

// Quarter-wave gather pipeline primitives (agg_mlp / spmm2; both kernels use
// identical local names scol/sw/wave/qw/ql/xb4/a).
// ISSUE: fire 4 uint4 loads (16 neighbors). CONSUME: weights * staged regs.
// Used ONLY in a tight post-dedupe loop (issue adjacent to consume) -> short
// live ranges, fits the 64-VGPR bounds(1024,8) budget (r10 measured 40 VGPR
// for this exact loop; r9's spill came from pre-issuing ACROSS the dedupe).
#define ISSUE(V, b_)                                                        \
    {                                                                       \
        _Pragma("unroll")                                                   \
        for (int u_ = 0; u_ < 4; ++u_)                                      \
            V[u_] = xb4[(size_t)scol[wave][(b_) + u_ * 4 + qw] * 16 + ql];  \
    }
#define CONSUME(V, b_)                                                      \
    {                                                                       \
        _Pragma("unroll")                                                   \
        for (int u_ = 0; u_ < 4; ++u_) {                                    \
            float w_ = sw[wave][(b_) + u_ * 4 + qw];                        \
            _Pragma("unroll")                                               \
            for (int m_ = 0; m_ < 4; ++m_) {                                \
                a[2 * m_]     += w_ * bf_lo(V[u_][m_]);                     \
                a[2 * m_ + 1] += w_ * bf_hi(V[u_][m_]);                     \
            }                                                               \
        }                                                                   \
    }

// Depth-2 A/B pipelined gather (post-dedupe: scol AND sw both ready).
// Keeps 4-8 uint4 loads in flight per wave vs r8's 4-issue-then-drain.
#define PIPEGATHER(dd_)                                                     \
    {                                                                       \
        u32x4 vA[4], vB[4];                                                 \
        int j_ = 0;                                                         \
        if ((dd_) >= 16) { ISSUE(vA, 0); }                                  \
        if ((dd_) >= 32) { ISSUE(vB, 16); }                                 \
        for (; j_ + 32 <= (dd_); j_ += 32) {                                \
            CONSUME(vA, j_);                                                \
            if (j_ + 48 <= (dd_)) { ISSUE(vA, j_ + 32); }                   \
            CONSUME(vB, j_ + 16);                                           \
            if (j_ + 64 <= (dd_)) { ISSUE(vB, j_ + 48); }                   \
        }                                                                   \
        if (j_ + 16 <= (dd_)) { CONSUME(vA, j_); j_ += 16; }                \
        for (; j_ + 4 <= (dd_); j_ += 4) {                                  \
            int n_ = j_ + qw;                                               \
            int c_ = scol[wave][n_]; float w_ = sw[wave][n_];               \
            u32x4 v_ = xb4[(size_t)c_ * 16 + ql];                           \
            _Pragma("unroll")                                               \
            for (int m_ = 0; m_ < 4; ++m_) {                                \
                a[2 * m_]     += w_ * bf_lo(v_[m_]);                        \
                a[2 * m_ + 1] += w_ * bf_hi(v_[m_]);                        \
            }                                                               \
        }                                                                   \
        int rem_ = (dd_) - j_;                                              \
        if (rem_ > 0) {                                                     \
            int n_ = j_ + (qw < rem_ ? qw : 0);                             \
            float w_ = (qw < rem_) ? sw[wave][n_] : 0.0f;                   \
            int c_ = scol[wave][n_];                                        \
            u32x4 v_ = xb4[(size_t)c_ * 16 + ql];                           \
            _Pragma("unroll")                                               \
            for (int m_ = 0; m_ < 4; ++m_) {                                \
                a[2 * m_]     += w_ * bf_lo(v_[m_]);                        \
                a[2 * m_ + 1] += w_ * bf_hi(v_[m_]);                        \
            }                                                               \
        }                                                                   \
        _Pragma("unroll")                                                   \
        for (int k_ = 0; k_ < 8; ++k_) {                                    \
            a[k_] += __shfl_xor(a[k_], 16, 64);                             \
            a[k_] += __shfl_xor(a[k_], 32, 64);                             \
        }                                                                   \
    }

// ---------------------------------------------------------------------------
// Tiny prologue: zero cur (blocks 0..63) + detect int64 vs int32 edge_index
// (block 64: odd u32 words all zero => int64).
__global__ void pre_small_kernel(int* __restrict__ cur, const unsigned* __restrict__ ei,
                                 int* __restrict__ mode) {
    int b = blockIdx.x, t = threadIdx.x;
    if (b < 64) {
        cur[b * 256 + t] = 0;
    } else {
        __shared__ int nz;
        if (t == 0) nz = 0;
        __syncthreads();
        for (int it = 0; it < 4; ++it) {
            int idx = 2 * (t + it * 256) + 1;
            if (ei[idx] != 0u) nz = 1;        // benign race
        }
        __syncthreads();
        if (t == 0) *mode = (nz == 0) ? 1 : 0;  // 1 => int64
    }
}

// ---------------------------------------------------------------------------
// Fused prep: ELL fill + x fp32->bf16 (row-major) + W1/W2 transpose-to-bf16.
__global__ void prep_fill_kernel(const void* __restrict__ ei, const int* __restrict__ mode,
                                 int* __restrict__ cur, int2* __restrict__ ed, int E, int nF,
                                 const float* __restrict__ x, unsigned short* __restrict__ xb,
                                 const float* __restrict__ W1, unsigned short* __restrict__ W1t,
                                 const float* __restrict__ W2, unsigned short* __restrict__ W2t) {
    int b = blockIdx.x, t = threadIdx.x;
    if (b < nF) {
        int base = b * 1024 + t;
        int m = *mode;
#pragma unroll
        for (int u = 0; u < 4; ++u) {
            int e = base + u * 256;
            if (e >= E) continue;
            int r, c;
            if (m) {
                const long long* p = (const long long*)ei;
                r = (int)p[e]; c = (int)p[e + E];
            } else {
                const int* p = (const int*)ei;
                r = p[e]; c = p[e + E];
            }
            if (((unsigned)r | (unsigned)c) >= N_NODES) continue;   // replay-safety guard
            int pos = atomicAdd(&cur[r], 1);
            if (pos < CAP) ed[r * CAP + pos] = make_int2(c, e);
        }
    } else if (b < nF + 2048) {
        int i = ((b - nF) * 256 + t) * 4;
        float4 v = *(const float4*)&x[i];
        ushort4 o;
        o.x = bf16rne(v.x); o.y = bf16rne(v.y); o.z = bf16rne(v.z); o.w = bf16rne(v.w);
        *(ushort4*)&xb[i] = o;
    } else if (b < nF + 2176) {
        int id = (b - nF - 2048) * 256 + t;   // [0, 32768)
        int n = id >> 7, k = id & 127;
        W1t[id] = bf16rne(W1[(size_t)k * F_HID + n]);
    } else {
        int id = (b - nF - 2176) * 256 + t;   // [0, 32768)
        int n = id >> 8, k = id & 255;
        W2t[id] = bf16rne(W2[(size_t)k * F_OUT + n]);
    }
}

// ---------------------------------------------------------------------------
// Fused dedupe + SpMM1 + MLP (round-8 structure + post-dedupe depth-2 gather
// pipeline). 16 rows/block, 16 waves (1024 thr), 1 row/wave.
__launch_bounds__(1024, 8)
__global__ void agg_mlp_kernel(const float* __restrict__ ew, int* __restrict__ cur,
                               int2* __restrict__ ed, float* __restrict__ invdeg,
                               const unsigned* __restrict__ xb,
                               const unsigned short* __restrict__ W1t,
                               const unsigned short* __restrict__ W2t,
                               const float* __restrict__ b1,
                               const float* __restrict__ ln_g, const float* __restrict__ ln_b,
                               unsigned short* __restrict__ h2b) {
    __shared__ int   scol[16][CAP];             // 8 KB
    __shared__ int   seid[16][CAP];             // 8 KB
    __shared__ float sw[16][CAP];               // 8 KB
    __shared__ unsigned short H0[16 * H0STR];   // 4.25 KB; reused as C2 repack
    __shared__ unsigned short H1[16 * H1STR];   // 8.25 KB
    __shared__ float red[2][16][16];            // 2 KB  (LN partial {s,q}[wave][row])

    int t = threadIdx.x, wave = t >> 6, lane = t & 63;
    int lnid = lane & 15, quad = lane >> 4;
    int qw = lane >> 4, ql = lane & 15;         // quarter id / lane-in-quarter
    int Rbase = blockIdx.x * 16;
    int r = Rbase + wave;

    // ---- stage {col, edge_id} of this wave's row into wave-private LDS ----
    int d = cur[r];
    if (d > CAP) d = CAP;
    int dpad = (d + 15) & ~15;
    int2* row = ed + (size_t)r * CAP;
    for (int i = lane; i < d; i += 64) {
        int2 e = row[i];
        scol[wave][i] = e.x;
        seid[wave][i] = e.y;
    }
    for (int i = d + lane; i < dpad; i += 64) {   // sentinel pad for 16-wide compare
        scol[wave][i] = -2;
        seid[wave][i] = 0;
    }
    asm volatile("s_waitcnt lgkmcnt(0)" ::: "memory");   // wave-local LDS ordering

    // ---- last-edge-wins dedupe + weight gather (batched 16-wide compares) ----
    float wsum = 0.0f;
    for (int i = lane; i < d; i += 64) {
        int myc = scol[wave][i], mye = seid[wave][i];
        bool kill = false;
        for (int jb = 0; jb < dpad; jb += 16) {
            const int* cb = &scol[wave][jb];
            const int* eb = &seid[wave][jb];
            i32x4 c0 = *(const i32x4*)(cb);
            i32x4 c1 = *(const i32x4*)(cb + 4);
            i32x4 c2 = *(const i32x4*)(cb + 8);
            i32x4 c3 = *(const i32x4*)(cb + 12);
            i32x4 e0 = *(const i32x4*)(eb);
            i32x4 e1 = *(const i32x4*)(eb + 4);
            i32x4 e2 = *(const i32x4*)(eb + 8);
            i32x4 e3 = *(const i32x4*)(eb + 12);
            kill |= (c0.x == myc && e0.x > mye);
            kill |= (c0.y == myc && e0.y > mye);
            kill |= (c0.z == myc && e0.z > mye);
            kill |= (c0.w == myc && e0.w > mye);
            kill |= (c1.x == myc && e1.x > mye);
            kill |= (c1.y == myc && e1.y > mye);
            kill |= (c1.z == myc && e1.z > mye);
            kill |= (c1.w == myc && e1.w > mye);
            kill |= (c2.x == myc && e2.x > mye);
            kill |= (c2.y == myc && e2.y > mye);
            kill |= (c2.z == myc && e2.z > mye);
            kill |= (c2.w == myc && e2.w > mye);
            kill |= (c3.x == myc && e3.x > mye);
            kill |= (c3.y == myc && e3.y > mye);
            kill |= (c3.z == myc && e3.z > mye);
            kill |= (c3.w == myc && e3.w > mye);
        }
        float w = kill ? 0.0f : ew[mye];
        sw[wave][i] = w;
        row[i] = make_int2(myc, __float_as_int(w));   // full 8B store (no RMW)
        wsum += w;
    }
    asm volatile("s_waitcnt lgkmcnt(0)" ::: "memory");
    for (int off = 32; off; off >>= 1) wsum += __shfl_xor(wsum, off, 64);
    float inv = 1.0f / (1.0f + wsum);                // +1 self-loop; >=1 so clip no-op
    if (lane == 0) { invdeg[r] = inv; cur[r] = d; }

    // ---- depth-2 pipelined quarter-wave uint4 gather-SpMM ----
    const u32x4* xb4 = (const u32x4*)xb;             // 16 B units; node row = 16 units
    float a[8] = {0, 0, 0, 0, 0, 0, 0, 0};
    PIPEGATHER(d);
    if (qw == 0) {                                   // + self, scale, bf16, H0 write
        u32x4 sv = xb4[(size_t)r * 16 + ql];
        u32x4 o;
#pragma unroll
        for (int m = 0; m < 4; ++m) {
            float lo = (a[2 * m]     + bf_lo(sv[m])) * inv;
            float hi = (a[2 * m + 1] + bf_hi(sv[m])) * inv;
            o[m] = ((unsigned)bf16rne(hi) << 16) | (unsigned)bf16rne(lo);
        }
        *(u32x4*)&H0[wave * H0STR + ql * 8] = o;     // 16 B aligned (H0STR=136)
    }
    __syncthreads();   // all 16 h0 rows staged

    // ---- stage A: C1[16x256] = h0 @ W1, K=128; wave handles ct = wave ----
    bf16x8 afr[4];
#pragma unroll
    for (int ch = 0; ch < 4; ++ch)
        afr[ch] = *(const bf16x8*)&H0[lnid * H0STR + ch * 32 + quad * 8];
    f32x4 acc = {0.0f, 0.0f, 0.0f, 0.0f};
    {
        const unsigned short* wrow = &W1t[(size_t)(wave * 16 + lnid) * F_IN];
#pragma unroll
        for (int ch = 0; ch < 4; ++ch) {
            bf16x8 b = *(const bf16x8*)&wrow[ch * 32 + quad * 8];
            acc = __builtin_amdgcn_mfma_f32_16x16x32_bf16(afr[ch], b, acc, 0, 0, 0);
        }
    }
    // bias + LN partial stats (rows in (quad,reg); this wave's 16 cols in lnid)
    float s[4], q[4];
    {
        float bv = b1[wave * 16 + lnid];
#pragma unroll
        for (int rr = 0; rr < 4; ++rr) {
            float v = acc[rr] + bv;
            acc[rr] = v;
            s[rr] = v; q[rr] = v * v;
        }
    }
#pragma unroll
    for (int rr = 0; rr < 4; ++rr)
        for (int off = 1; off < 16; off <<= 1) {
            s[rr] += __shfl_xor(s[rr], off, 64);
            q[rr] += __shfl_xor(q[rr], off, 64);
        }
    if (lnid == 0) {
#pragma unroll
        for (int rr = 0; rr < 4; ++rr) {
            red[0][wave][quad * 4 + rr] = s[rr];
            red[1][wave][quad * 4 + rr] = q[rr];
        }
    }
    __syncthreads();
    float mean[4], rinv[4];
#pragma unroll
    for (int rr = 0; rr < 4; ++rr) {
        int rowi = quad * 4 + rr;
        float S = 0.0f, Q = 0.0f;
#pragma unroll
        for (int w2 = 0; w2 < 16; ++w2) { S += red[0][w2][rowi]; Q += red[1][w2][rowi]; }
        mean[rr] = S * (1.0f / F_HID);
        float var = Q * (1.0f / F_HID) - mean[rr] * mean[rr];
        rinv[rr] = rsqrtf(var + LN_EPS);
    }
    {
        int c = wave * 16 + lnid;
        float g = ln_g[c], bb = ln_b[c];
#pragma unroll
        for (int rr = 0; rr < 4; ++rr) {
            float v = fmaxf((acc[rr] - mean[rr]) * rinv[rr] * g + bb, 0.0f);
            H1[(quad * 4 + rr) * H1STR + c] = bf16rne(v);
        }
    }
    __syncthreads();   // H1 complete; H0 a-frags long consumed -> reusable

    // ---- stage B: C2[16x128] = H1 @ W2, K=256; waves 0-7, ct = wave ----
    unsigned short* rep = H0;   // repack area (16 x REPSTR fits in 16 x H0STR)
    if (wave < 8) {
        bf16x8 a2[8];
#pragma unroll
        for (int ch = 0; ch < 8; ++ch)
            a2[ch] = *(const bf16x8*)&H1[lnid * H1STR + ch * 32 + quad * 8];
        f32x4 c2 = {0.0f, 0.0f, 0.0f, 0.0f};
        const unsigned short* wrow = &W2t[(size_t)(wave * 16 + lnid) * F_HID];
#pragma unroll
        for (int ch = 0; ch < 8; ++ch) {
            bf16x8 b = *(const bf16x8*)&wrow[ch * 32 + quad * 8];
            c2 = __builtin_amdgcn_mfma_f32_16x16x32_bf16(a2[ch], b, c2, 0, 0, 0);
        }
#pragma unroll
        for (int rr = 0; rr < 4; ++rr)
            rep[(quad * 4 + rr) * REPSTR + wave * 16 + lnid] = bf16rne(c2[rr]);
    }
    __syncthreads();   // drain before coalesced readback

    // coalesced store: 16 rows x 128 bf16 (512 ushort4, threads 0..511)
    if (t < 512) {
        int m = t >> 5, cg = t & 31;
        *(ushort4*)&h2b[(size_t)(Rbase + m) * F_OUT + cg * 4] =
            *(const ushort4*)&rep[m * REPSTR + cg * 4];
    }
}

// ---------------------------------------------------------------------------
// Gather SpMM (ELL, deduped weights in ed.y): 16 waves/block, 1 row/wave,
// row staged in LDS, depth-2 pipelined quarter-wave uint4 gathers.
__launch_bounds__(1024, 8)
__global__ void spmm2_kernel(const unsigned* __restrict__ xb, const int* __restrict__ cur,
                             const int2* __restrict__ ed, const float* __restrict__ invdeg,
                             const float* __restrict__ bias, float* __restrict__ outp) {
    __shared__ int   scol[16][CAP];             // 8 KB
    __shared__ float sw[16][CAP];               // 8 KB
    int t = threadIdx.x, wave = t >> 6, lane = t & 63;
    int qw = lane >> 4, ql = lane & 15;
    int r = blockIdx.x * 16 + wave;
    const int2* row = ed + (size_t)r * CAP;
    int d = cur[r];
    if (d > CAP) d = CAP;
    for (int i = lane; i < d; i += 64) {
        int2 e = row[i];
        scol[wave][i] = e.x;
        sw[wave][i] = __int_as_float(e.y);
    }
    asm volatile("s_waitcnt lgkmcnt(0)" ::: "memory");   // wave-local LDS ordering

    const u32x4* xb4 = (const u32x4*)xb;
    float a[8] = {0, 0, 0, 0, 0, 0, 0, 0};
    PIPEGATHER(d);
    if (qw == 0) {                                   // + self, scale, bias, store
        float inv = invdeg[r];
        u32x4 sv = xb4[(size_t)r * 16 + ql];
        int f = ql * 8;
        f32x4 o0, o1;
#pragma unroll
        for (int m = 0; m < 2; ++m) {
            o0[2 * m]     = (a[2 * m]     + bf_lo(sv[m])) * inv + bias[f + 2 * m];
            o0[2 * m + 1] = (a[2 * m + 1] + bf_hi(sv[m])) * inv + bias[f + 2 * m + 1];
        }
#pragma unroll
        for (int m = 2; m < 4; ++m) {
            o1[2 * m - 4] = (a[2 * m]     + bf_lo(sv[m])) * inv + bias[f + 2 * m];
            o1[2 * m - 3] = (a[2 * m + 1] + bf_hi(sv[m])) * inv + bias[f + 2 * m + 1];
        }
        *(f32x4*)&outp[(size_t)r * F_OUT + f]     = o0;
        *(f32x4*)&outp[(size_t)r * F_OUT + f + 4] = o1;
    }
}

// ---------------------------------------------------------------------------
extern "C" void kernel_launch(void* const* d_in, const int* in_sizes, int n_in,
                              void* d_out, int out_size, void* d_ws, size_t ws_size,
                              hipStream_t stream) {
    const float* x   = (const float*)d_in[0];
    const void*  ei  = d_in[1];
    const float* ew  = (const float*)d_in[2];
    const float* W1  = (const float*)d_in[3];
    const float* b1  = (const float*)d_in[4];
    const float* W2  = (const float*)d_in[5];
    const float* b2  = (const float*)d_in[6];
    const float* lng = (const float*)d_in[7];
    const float* lnb = (const float*)d_in[8];
    float* out = (float*)d_out;
    int E = in_sizes[2];

    char* w = (char*)d_ws;
    size_t off = 0;
    auto take = [&](size_t bytes) -> char* {
        char* p = w + off;
        off += (bytes + 255) & ~(size_t)255;
        return p;
    };
    int*   cur    = (int*)take((size_t)N_NODES * 4);
    float* invdeg = (float*)take((size_t)N_NODES * 4);
    int2*  ed     = (int2*)take((size_t)N_NODES * CAP * 8);
    unsigned short* xb  = (unsigned short*)take((size_t)N_NODES * F_IN * 2);
    unsigned short* h2b = (unsigned short*)take((size_t)N_NODES * F_OUT * 2);
    unsigned short* W1t = (unsigned short*)take((size_t)F_IN * F_HID * 2);
    unsigned short* W2t = (unsigned short*)take((size_t)F_HID * F_OUT * 2);
    int*   mode   = (int*)take(4);

    int nF = (E + 1023) / 1024;
    pre_small_kernel<<<65, 256, 0, stream>>>(cur, (const unsigned*)ei, mode);
    prep_fill_kernel<<<nF + 2304, 256, 0, stream>>>(ei, mode, cur, ed, E, nF,
                                                    x, xb, W1, W1t, W2, W2t);
    // h0 = bf16( D^-1 (A+I) x ) stays in LDS; h2b = bf16( relu(LN(h0 W1 + b1)) W2 )
    agg_mlp_kernel<<<N_NODES / 16, 1024, 0, stream>>>(ew, cur, ed, invdeg,
                                                      (const unsigned*)xb, W1t, W2t,
                                                      b1, lng, lnb, h2b);
    // out = D^-1 (A+I) h2 + b2   (== (D^-1 (A+I) h) W2 + b2 by linearity)
    spmm2_kernel<<<N_NODES / 16, 1024, 0, stream>>>((const unsigned*)h2b, cur, ed, invdeg,
                                                    b2, out);
}

// Round 15
// 182.221 us; speedup vs baseline: 1.4220x; 1.4220x over previous
//
#include <hip/hip_runtime.h>

#define N_NODES 16384
#define F_IN    128
#define F_HID   256
#define F_OUT   128
#define LN_EPS  1e-5f
#define CAP     128   // ELL slots/row; P(deg>128) ~ 1e-20 for Poisson(32)
#define H0STR   136   // LDS h0 stride (ushorts); 272 B = 17x16 -> 16B-aligned rows
#define H1STR   264   // LDS post-LN stride (ushorts)
#define REPSTR  132   // LDS C2 repack stride (ushorts)

typedef __attribute__((ext_vector_type(8))) short bf16x8;
typedef __attribute__((ext_vector_type(4))) float f32x4;
typedef __attribute__((ext_vector_type(4))) int   i32x4;
typedef __attribute__((ext_vector_type(4))) unsigned u32x4;

__device__ __forceinline__ unsigned short bf16rne(float f) {
    unsigned u = __float_as_uint(f);
    unsigned r = (u + 0x7fffu + ((u >> 16) & 1u)) >> 16;   // round-to-nearest-even
    return (unsigned short)r;
}
__device__ __forceinline__ float bf_lo(unsigned v) { return __uint_as_float(v << 16); }
__device__ __forceinline__ float bf_hi(unsigned v) { return __uint_as_float(v & 0xffff0000u); }

// ---------------------------------------------------------------------------
// Tiny prologue: zero cur (blocks 0..63) + detect int64 vs int32 edge_index
// (block 64: odd u32 words all zero => int64).
__global__ void pre_small_kernel(int* __restrict__ cur, const unsigned* __restrict__ ei,
                                 int* __restrict__ mode) {
    int b = blockIdx.x, t = threadIdx.x;
    if (b < 64) {
        cur[b * 256 + t] = 0;
    } else {
        __shared__ int nz;
        if (t == 0) nz = 0;
        __syncthreads();
        for (int it = 0; it < 4; ++it) {
            int idx = 2 * (t + it * 256) + 1;
            if (ei[idx] != 0u) nz = 1;        // benign race
        }
        __syncthreads();
        if (t == 0) *mode = (nz == 0) ? 1 : 0;  // 1 => int64
    }
}

// ---------------------------------------------------------------------------
// Fused prep: ELL fill + x fp32->bf16 (row-major) + W1/W2 transpose-to-bf16.
__global__ void prep_fill_kernel(const void* __restrict__ ei, const int* __restrict__ mode,
                                 int* __restrict__ cur, int2* __restrict__ ed, int E, int nF,
                                 const float* __restrict__ x, unsigned short* __restrict__ xb,
                                 const float* __restrict__ W1, unsigned short* __restrict__ W1t,
                                 const float* __restrict__ W2, unsigned short* __restrict__ W2t) {
    int b = blockIdx.x, t = threadIdx.x;
    if (b < nF) {
        int base = b * 1024 + t;
        int m = *mode;
#pragma unroll
        for (int u = 0; u < 4; ++u) {
            int e = base + u * 256;
            if (e >= E) continue;
            int r, c;
            if (m) {
                const long long* p = (const long long*)ei;
                r = (int)p[e]; c = (int)p[e + E];
            } else {
                const int* p = (const int*)ei;
                r = p[e]; c = p[e + E];
            }
            if (((unsigned)r | (unsigned)c) >= N_NODES) continue;   // replay-safety guard
            int pos = atomicAdd(&cur[r], 1);
            if (pos < CAP) ed[r * CAP + pos] = make_int2(c, e);
        }
    } else if (b < nF + 2048) {
        int i = ((b - nF) * 256 + t) * 4;
        float4 v = *(const float4*)&x[i];
        ushort4 o;
        o.x = bf16rne(v.x); o.y = bf16rne(v.y); o.z = bf16rne(v.z); o.w = bf16rne(v.w);
        *(ushort4*)&xb[i] = o;
    } else if (b < nF + 2176) {
        int id = (b - nF - 2048) * 256 + t;   // [0, 32768)
        int n = id >> 7, k = id & 127;
        W1t[id] = bf16rne(W1[(size_t)k * F_HID + n]);
    } else {
        int id = (b - nF - 2176) * 256 + t;   // [0, 32768)
        int n = id >> 8, k = id & 255;
        W2t[id] = bf16rne(W2[(size_t)k * F_OUT + n]);
    }
}

// ---------------------------------------------------------------------------
// Fused dedupe + SpMM1 + MLP (round-8 structure, best measured: 182.3 us
// total, agg 59.5 us). 16 rows/block, 16 waves (1024 thr), 1 row/wave.
// Quarter-wave uint4 gathers: one load = 16B = 8 feats of 1 neighbor, 4
// quarters cover 4 neighbors/load-slot; quarters combined via shfl_xor(16,32).
// Dedupe: batched 16-wide compares (order-independent kill, bit-identical).
// NOTE structural floor (r1-r14 ablations): gather phase is pinned at
// ~1.3 TB/s FETCH rate across occupancy/instr-count/pipeline/L2-capacity/
// footprint variants -> per-CU outstanding-miss (latency-queue) limit.
// Deeper per-wave pipelining spills (compiler pins 32 VGPR under
// bounds(1024,8): r9/r14 = 194-273 MB scratch WRITE); lower bounds halves
// occupancy (r10). This version is the measured optimum of the family.
__launch_bounds__(1024, 8)
__global__ void agg_mlp_kernel(const float* __restrict__ ew, int* __restrict__ cur,
                               int2* __restrict__ ed, float* __restrict__ invdeg,
                               const unsigned* __restrict__ xb,
                               const unsigned short* __restrict__ W1t,
                               const unsigned short* __restrict__ W2t,
                               const float* __restrict__ b1,
                               const float* __restrict__ ln_g, const float* __restrict__ ln_b,
                               unsigned short* __restrict__ h2b) {
    __shared__ int   scol[16][CAP];             // 8 KB
    __shared__ int   seid[16][CAP];             // 8 KB
    __shared__ float sw[16][CAP];               // 8 KB
    __shared__ unsigned short H0[16 * H0STR];   // 4.25 KB; reused as C2 repack
    __shared__ unsigned short H1[16 * H1STR];   // 8.25 KB
    __shared__ float red[2][16][16];            // 2 KB  (LN partial {s,q}[wave][row])

    int t = threadIdx.x, wave = t >> 6, lane = t & 63;
    int lnid = lane & 15, quad = lane >> 4;
    int qw = lane >> 4, ql = lane & 15;         // quarter id / lane-in-quarter
    int Rbase = blockIdx.x * 16;
    int r = Rbase + wave;

    // ---- stage {col, edge_id} of this wave's row into wave-private LDS ----
    int d = cur[r];
    if (d > CAP) d = CAP;
    int dpad = (d + 15) & ~15;
    int2* row = ed + (size_t)r * CAP;
    for (int i = lane; i < d; i += 64) {
        int2 e = row[i];
        scol[wave][i] = e.x;
        seid[wave][i] = e.y;
    }
    for (int i = d + lane; i < dpad; i += 64) {   // sentinel pad for 16-wide compare
        scol[wave][i] = -2;
        seid[wave][i] = 0;
    }
    asm volatile("s_waitcnt lgkmcnt(0)" ::: "memory");   // wave-local LDS ordering

    // ---- last-edge-wins dedupe + weight gather (batched 16-wide compares) ----
    float wsum = 0.0f;
    for (int i = lane; i < d; i += 64) {
        int myc = scol[wave][i], mye = seid[wave][i];
        bool kill = false;
        for (int jb = 0; jb < dpad; jb += 16) {
            const int* cb = &scol[wave][jb];
            const int* eb = &seid[wave][jb];
            i32x4 c0 = *(const i32x4*)(cb);
            i32x4 c1 = *(const i32x4*)(cb + 4);
            i32x4 c2 = *(const i32x4*)(cb + 8);
            i32x4 c3 = *(const i32x4*)(cb + 12);
            i32x4 e0 = *(const i32x4*)(eb);
            i32x4 e1 = *(const i32x4*)(eb + 4);
            i32x4 e2 = *(const i32x4*)(eb + 8);
            i32x4 e3 = *(const i32x4*)(eb + 12);
            kill |= (c0.x == myc && e0.x > mye);
            kill |= (c0.y == myc && e0.y > mye);
            kill |= (c0.z == myc && e0.z > mye);
            kill |= (c0.w == myc && e0.w > mye);
            kill |= (c1.x == myc && e1.x > mye);
            kill |= (c1.y == myc && e1.y > mye);
            kill |= (c1.z == myc && e1.z > mye);
            kill |= (c1.w == myc && e1.w > mye);
            kill |= (c2.x == myc && e2.x > mye);
            kill |= (c2.y == myc && e2.y > mye);
            kill |= (c2.z == myc && e2.z > mye);
            kill |= (c2.w == myc && e2.w > mye);
            kill |= (c3.x == myc && e3.x > mye);
            kill |= (c3.y == myc && e3.y > mye);
            kill |= (c3.z == myc && e3.z > mye);
            kill |= (c3.w == myc && e3.w > mye);
        }
        float w = kill ? 0.0f : ew[mye];
        sw[wave][i] = w;
        row[i] = make_int2(myc, __float_as_int(w));   // full 8B store (no RMW)
        wsum += w;
    }
    asm volatile("s_waitcnt lgkmcnt(0)" ::: "memory");
    for (int off = 32; off; off >>= 1) wsum += __shfl_xor(wsum, off, 64);
    float inv = 1.0f / (1.0f + wsum);                // +1 self-loop; >=1 so clip no-op
    if (lane == 0) { invdeg[r] = inv; cur[r] = d; }

    // ---- quarter-wave uint4 gather-SpMM: lane covers feats [ql*8, ql*8+8) ----
    const u32x4* xb4 = (const u32x4*)xb;             // 16 B units; node row = 16 units
    float a[8] = {0, 0, 0, 0, 0, 0, 0, 0};
    int j = 0;
    for (; j + 16 <= d; j += 16) {                   // 16 neighbors / 4 loads in flight
        int c[4]; float w[4]; u32x4 v[4];
#pragma unroll
        for (int u = 0; u < 4; ++u) {
            int n = j + u * 4 + qw;
            c[u] = scol[wave][n];
            w[u] = sw[wave][n];
        }
#pragma unroll
        for (int u = 0; u < 4; ++u) v[u] = xb4[(size_t)c[u] * 16 + ql];
#pragma unroll
        for (int u = 0; u < 4; ++u)
#pragma unroll
            for (int m = 0; m < 4; ++m) {
                a[2 * m]     += w[u] * bf_lo(v[u][m]);
                a[2 * m + 1] += w[u] * bf_hi(v[u][m]);
            }
    }
    for (; j + 4 <= d; j += 4) {                     // 4-neighbor tail
        int n = j + qw;
        int c = scol[wave][n];
        float w = sw[wave][n];
        u32x4 v = xb4[(size_t)c * 16 + ql];
#pragma unroll
        for (int m = 0; m < 4; ++m) {
            a[2 * m]     += w * bf_lo(v[m]);
            a[2 * m + 1] += w * bf_hi(v[m]);
        }
    }
    int rem = d - j;
    if (rem > 0) {                                   // <4 tail: idle quarters w=0
        int n = j + (qw < rem ? qw : 0);
        float w = (qw < rem) ? sw[wave][n] : 0.0f;
        int c = scol[wave][n];
        u32x4 v = xb4[(size_t)c * 16 + ql];
#pragma unroll
        for (int m = 0; m < 4; ++m) {
            a[2 * m]     += w * bf_lo(v[m]);
            a[2 * m + 1] += w * bf_hi(v[m]);
        }
    }
#pragma unroll
    for (int k = 0; k < 8; ++k) {                    // combine the 4 quarters
        a[k] += __shfl_xor(a[k], 16, 64);
        a[k] += __shfl_xor(a[k], 32, 64);
    }
    if (qw == 0) {                                   // + self, scale, bf16, H0 write
        u32x4 sv = xb4[(size_t)r * 16 + ql];
        u32x4 o;
#pragma unroll
        for (int m = 0; m < 4; ++m) {
            float lo = (a[2 * m]     + bf_lo(sv[m])) * inv;
            float hi = (a[2 * m + 1] + bf_hi(sv[m])) * inv;
            o[m] = ((unsigned)bf16rne(hi) << 16) | (unsigned)bf16rne(lo);
        }
        *(u32x4*)&H0[wave * H0STR + ql * 8] = o;     // 16 B aligned (H0STR=136)
    }
    __syncthreads();   // all 16 h0 rows staged

    // ---- stage A: C1[16x256] = h0 @ W1, K=128; wave handles ct = wave ----
    bf16x8 afr[4];
#pragma unroll
    for (int ch = 0; ch < 4; ++ch)
        afr[ch] = *(const bf16x8*)&H0[lnid * H0STR + ch * 32 + quad * 8];
    f32x4 acc = {0.0f, 0.0f, 0.0f, 0.0f};
    {
        const unsigned short* wrow = &W1t[(size_t)(wave * 16 + lnid) * F_IN];
#pragma unroll
        for (int ch = 0; ch < 4; ++ch) {
            bf16x8 b = *(const bf16x8*)&wrow[ch * 32 + quad * 8];
            acc = __builtin_amdgcn_mfma_f32_16x16x32_bf16(afr[ch], b, acc, 0, 0, 0);
        }
    }
    // bias + LN partial stats (rows in (quad,reg); this wave's 16 cols in lnid)
    float s[4], q[4];
    {
        float bv = b1[wave * 16 + lnid];
#pragma unroll
        for (int rr = 0; rr < 4; ++rr) {
            float v = acc[rr] + bv;
            acc[rr] = v;
            s[rr] = v; q[rr] = v * v;
        }
    }
#pragma unroll
    for (int rr = 0; rr < 4; ++rr)
        for (int off = 1; off < 16; off <<= 1) {
            s[rr] += __shfl_xor(s[rr], off, 64);
            q[rr] += __shfl_xor(q[rr], off, 64);
        }
    if (lnid == 0) {
#pragma unroll
        for (int rr = 0; rr < 4; ++rr) {
            red[0][wave][quad * 4 + rr] = s[rr];
            red[1][wave][quad * 4 + rr] = q[rr];
        }
    }
    __syncthreads();
    float mean[4], rinv[4];
#pragma unroll
    for (int rr = 0; rr < 4; ++rr) {
        int rowi = quad * 4 + rr;
        float S = 0.0f, Q = 0.0f;
#pragma unroll
        for (int w2 = 0; w2 < 16; ++w2) { S += red[0][w2][rowi]; Q += red[1][w2][rowi]; }
        mean[rr] = S * (1.0f / F_HID);
        float var = Q * (1.0f / F_HID) - mean[rr] * mean[rr];
        rinv[rr] = rsqrtf(var + LN_EPS);
    }
    {
        int c = wave * 16 + lnid;
        float g = ln_g[c], bb = ln_b[c];
#pragma unroll
        for (int rr = 0; rr < 4; ++rr) {
            float v = fmaxf((acc[rr] - mean[rr]) * rinv[rr] * g + bb, 0.0f);
            H1[(quad * 4 + rr) * H1STR + c] = bf16rne(v);
        }
    }
    __syncthreads();   // H1 complete; H0 a-frags long consumed -> reusable

    // ---- stage B: C2[16x128] = H1 @ W2, K=256; waves 0-7, ct = wave ----
    unsigned short* rep = H0;   // repack area (16 x REPSTR fits in 16 x H0STR)
    if (wave < 8) {
        bf16x8 a2[8];
#pragma unroll
        for (int ch = 0; ch < 8; ++ch)
            a2[ch] = *(const bf16x8*)&H1[lnid * H1STR + ch * 32 + quad * 8];
        f32x4 c2 = {0.0f, 0.0f, 0.0f, 0.0f};
        const unsigned short* wrow = &W2t[(size_t)(wave * 16 + lnid) * F_HID];
#pragma unroll
        for (int ch = 0; ch < 8; ++ch) {
            bf16x8 b = *(const bf16x8*)&wrow[ch * 32 + quad * 8];
            c2 = __builtin_amdgcn_mfma_f32_16x16x32_bf16(a2[ch], b, c2, 0, 0, 0);
        }
#pragma unroll
        for (int rr = 0; rr < 4; ++rr)
            rep[(quad * 4 + rr) * REPSTR + wave * 16 + lnid] = bf16rne(c2[rr]);
    }
    __syncthreads();   // drain before coalesced readback

    // coalesced store: 16 rows x 128 bf16 (512 ushort4, threads 0..511)
    if (t < 512) {
        int m = t >> 5, cg = t & 31;
        *(ushort4*)&h2b[(size_t)(Rbase + m) * F_OUT + cg * 4] =
            *(const ushort4*)&rep[m * REPSTR + cg * 4];
    }
}

// ---------------------------------------------------------------------------
// Gather SpMM (ELL, deduped weights in ed.y): 16 waves/block, 1 row/wave,
// row staged in LDS, quarter-wave uint4 gathers. out = acc*invdeg + bias.
__launch_bounds__(1024, 8)
__global__ void spmm2_kernel(const unsigned* __restrict__ xb, const int* __restrict__ cur,
                             const int2* __restrict__ ed, const float* __restrict__ invdeg,
                             const float* __restrict__ bias, float* __restrict__ outp) {
    __shared__ int   scol[16][CAP];             // 8 KB
    __shared__ float sw[16][CAP];               // 8 KB
    int t = threadIdx.x, wave = t >> 6, lane = t & 63;
    int qw = lane >> 4, ql = lane & 15;
    int r = blockIdx.x * 16 + wave;
    const int2* row = ed + (size_t)r * CAP;
    int d = cur[r];
    if (d > CAP) d = CAP;
    for (int i = lane; i < d; i += 64) {
        int2 e = row[i];
        scol[wave][i] = e.x;
        sw[wave][i] = __int_as_float(e.y);
    }
    asm volatile("s_waitcnt lgkmcnt(0)" ::: "memory");   // wave-local LDS ordering

    const u32x4* xb4 = (const u32x4*)xb;
    float a[8] = {0, 0, 0, 0, 0, 0, 0, 0};
    int j = 0;
    for (; j + 16 <= d; j += 16) {
        int c[4]; float w[4]; u32x4 v[4];
#pragma unroll
        for (int u = 0; u < 4; ++u) {
            int n = j + u * 4 + qw;
            c[u] = scol[wave][n];
            w[u] = sw[wave][n];
        }
#pragma unroll
        for (int u = 0; u < 4; ++u) v[u] = xb4[(size_t)c[u] * 16 + ql];
#pragma unroll
        for (int u = 0; u < 4; ++u)
#pragma unroll
            for (int m = 0; m < 4; ++m) {
                a[2 * m]     += w[u] * bf_lo(v[u][m]);
                a[2 * m + 1] += w[u] * bf_hi(v[u][m]);
            }
    }
    for (; j + 4 <= d; j += 4) {
        int n = j + qw;
        int c = scol[wave][n];
        float w = sw[wave][n];
        u32x4 v = xb4[(size_t)c * 16 + ql];
#pragma unroll
        for (int m = 0; m < 4; ++m) {
            a[2 * m]     += w * bf_lo(v[m]);
            a[2 * m + 1] += w * bf_hi(v[m]);
        }
    }
    int rem = d - j;
    if (rem > 0) {
        int n = j + (qw < rem ? qw : 0);
        float w = (qw < rem) ? sw[wave][n] : 0.0f;
        int c = scol[wave][n];
        u32x4 v = xb4[(size_t)c * 16 + ql];
#pragma unroll
        for (int m = 0; m < 4; ++m) {
            a[2 * m]     += w * bf_lo(v[m]);
            a[2 * m + 1] += w * bf_hi(v[m]);
        }
    }
#pragma unroll
    for (int k = 0; k < 8; ++k) {
        a[k] += __shfl_xor(a[k], 16, 64);
        a[k] += __shfl_xor(a[k], 32, 64);
    }
    if (qw == 0) {                                   // + self, scale, bias, store
        float inv = invdeg[r];
        u32x4 sv = xb4[(size_t)r * 16 + ql];
        int f = ql * 8;
        f32x4 o0, o1;
#pragma unroll
        for (int m = 0; m < 2; ++m) {
            o0[2 * m]     = (a[2 * m]     + bf_lo(sv[m])) * inv + bias[f + 2 * m];
            o0[2 * m + 1] = (a[2 * m + 1] + bf_hi(sv[m])) * inv + bias[f + 2 * m + 1];
        }
#pragma unroll
        for (int m = 2; m < 4; ++m) {
            o1[2 * m - 4] = (a[2 * m]     + bf_lo(sv[m])) * inv + bias[f + 2 * m];
            o1[2 * m - 3] = (a[2 * m + 1] + bf_hi(sv[m])) * inv + bias[f + 2 * m + 1];
        }
        *(f32x4*)&outp[(size_t)r * F_OUT + f]     = o0;
        *(f32x4*)&outp[(size_t)r * F_OUT + f + 4] = o1;
    }
}

// ---------------------------------------------------------------------------
extern "C" void kernel_launch(void* const* d_in, const int* in_sizes, int n_in,
                              void* d_out, int out_size, void* d_ws, size_t ws_size,
                              hipStream_t stream) {
    const float* x   = (const float*)d_in[0];
    const void*  ei  = d_in[1];
    const float* ew  = (const float*)d_in[2];
    const float* W1  = (const float*)d_in[3];
    const float* b1  = (const float*)d_in[4];
    const float* W2  = (const float*)d_in[5];
    const float* b2  = (const float*)d_in[6];
    const float* lng = (const float*)d_in[7];
    const float* lnb = (const float*)d_in[8];
    float* out = (float*)d_out;
    int E = in_sizes[2];

    char* w = (char*)d_ws;
    size_t off = 0;
    auto take = [&](size_t bytes) -> char* {
        char* p = w + off;
        off += (bytes + 255) & ~(size_t)255;
        return p;
    };
    int*   cur    = (int*)take((size_t)N_NODES * 4);
    float* invdeg = (float*)take((size_t)N_NODES * 4);
    int2*  ed     = (int2*)take((size_t)N_NODES * CAP * 8);
    unsigned short* xb  = (unsigned short*)take((size_t)N_NODES * F_IN * 2);
    unsigned short* h2b = (unsigned short*)take((size_t)N_NODES * F_OUT * 2);
    unsigned short* W1t = (unsigned short*)take((size_t)F_IN * F_HID * 2);
    unsigned short* W2t = (unsigned short*)take((size_t)F_HID * F_OUT * 2);
    int*   mode   = (int*)take(4);

    int nF = (E + 1023) / 1024;
    pre_small_kernel<<<65, 256, 0, stream>>>(cur, (const unsigned*)ei, mode);
    prep_fill_kernel<<<nF + 2304, 256, 0, stream>>>(ei, mode, cur, ed, E, nF,
                                                    x, xb, W1, W1t, W2, W2t);
    // h0 = bf16( D^-1 (A+I) x ) stays in LDS; h2b = bf16( relu(LN(h0 W1 + b1)) W2 )
    agg_mlp_kernel<<<N_NODES / 16, 1024, 0, stream>>>(ew, cur, ed, invdeg,
                                                      (const unsigned*)xb, W1t, W2t,
                                                      b1, lng, lnb, h2b);
    // out = D^-1 (A+I) h2 + b2   (== (D^-1 (A+I) h) W2 + b2 by linearity)
    spmm2_kernel<<<N_NODES / 16, 1024, 0, stream>>>((const unsigned*)h2b, cur, ed, invdeg,
                                                    b2, out);
}